// Round 5
// baseline (245.827 us; speedup 1.0000x reference)
//
#include <hip/hip_runtime.h>

// Problem: B=64, C=16, H=32, W=512, SHIFT=4 (9 offsets), MARGIN=0.15
#define NB 64
#define NC 16
#define NH 32
#define NW 512
#define HW (NH * NW)      // 16384
#define CHW (NC * HW)     // 262144
#define NOFF 9

// ws layout (floats): num_ap[64*9] | num_an[64*9] | cnt_ap[64*9] | cnt_an[64*9]
#define WS_NUM_AP 0
#define WS_NUM_AN 576
#define WS_CNT_AP 1152
#define WS_CNT_AN 1728
#define WS_FLOATS 2304

__device__ __forceinline__ float wave_sum_f(float v) {
#pragma unroll
    for (int o = 32; o > 0; o >>= 1) v += __shfl_down(v, o, 64);
    return v;
}

// Direct global->LDS, 16B per lane. LDS dest must be wave-uniform base (HW writes
// lane i at base + i*16); global src is per-lane.
__device__ __forceinline__ void stage16(const float* g, float* lds) {
    __builtin_amdgcn_global_load_lds(
        (const __attribute__((address_space(1))) void*)g,
        (__attribute__((address_space(3))) void*)lds,
        16, 0, 0);
}

// grid: (16, 4, 64).
//   blockIdx.x: position tile (block covers 1024 positions = 2 full rows of W=512)
//   blockIdx.y: bit0 = pair (0: a-p, 1: a-n), bit1 = channel group (8 channels each)
//   blockIdx.z: batch
//
// Round-4 pre-masked factorization kept (25 accumulators, no spill).
// NEW: F is staged into LDS via global_load_lds (unique bytes only), so the
// 3x-overlapped idxm/pos0/idxp reads become ds_read_b128 on the LDS pipe.
// This cuts global vector-port request volume ~604 -> ~335 MB (the measured
// binding resource in round 4: 7.3 TB/s ~= per-CU port ceiling).
// Double-buffered, 2 channels per round, 1 barrier per round; A prefetched
// one round ahead (issue-early / consume-late).
__global__ __launch_bounds__(256, 4) void num_kernel(
    const float* __restrict__ a, const float* __restrict__ p,
    const float* __restrict__ n, const int* __restrict__ ma,
    const int* __restrict__ mp, const int* __restrict__ mn,
    float* __restrict__ ws)
{
    const int b    = blockIdx.z;
    const int pair = blockIdx.y & 1;        // 0 -> p, 1 -> n
    const int cg   = blockIdx.y >> 1;       // channel group: 0 or 1
    const int lane = threadIdx.x & 63;
    const int wid  = threadIdx.x >> 6;

    const int blockStart = blockIdx.x * 1024;     // first position of this block
    const int lp   = threadIdx.x * 4;             // local position, 0..1023
    const int lrow = lp & ~(NW - 1);              // 0 or 512 (local row base)
    const int lw   = lp & (NW - 1);
    const int pos0 = blockStart + lp;             // global position
    const int grow = pos0 - lw;                   // global row base
    const int idxm = grow + ((lw - 4) & (NW - 1));
    const int idxp = grow + ((lw + 4) & (NW - 1));

    // ---- masks -> float multipliers ----
    const int* MA = ma + b * HW;
    const int* M2 = (pair ? mn : mp) + b * HW;
    int4 mav = *(const int4*)(MA + pos0);
    int4 mf0 = *(const int4*)(M2 + idxm);
    int4 mf1 = *(const int4*)(M2 + pos0);
    int4 mf2 = *(const int4*)(M2 + idxp);

    float m1f[4]  = {mav.x ? 1.f : 0.f, mav.y ? 1.f : 0.f,
                     mav.z ? 1.f : 0.f, mav.w ? 1.f : 0.f};
    float m2f[12] = {mf0.x ? 1.f : 0.f, mf0.y ? 1.f : 0.f, mf0.z ? 1.f : 0.f, mf0.w ? 1.f : 0.f,
                     mf1.x ? 1.f : 0.f, mf1.y ? 1.f : 0.f, mf1.z ? 1.f : 0.f, mf1.w ? 1.f : 0.f,
                     mf2.x ? 1.f : 0.f, mf2.y ? 1.f : 0.f, mf2.z ? 1.f : 0.f, mf2.w ? 1.f : 0.f};

    const float* A = a + (size_t)b * CHW + (size_t)cg * 8 * HW;
    const float* F = (pair ? n : p) + (size_t)b * CHW + (size_t)cg * 8 * HW;
    const float* AG = A + blockStart;   // + c*HW + lp
    const float* FG = F + blockStart;   // + c*HW + wid*256 + lane*4 (stage)

    // LDS: double buffer x 2 channels x 1024 floats = 16 KB, + reduction pad
    __shared__ float fbuf[2][2][1024];
    __shared__ float red[4][20];

    float sa2[4];
    float sf2[12];
    float crS[NOFF];
#pragma unroll
    for (int j = 0; j < 4; ++j) sa2[j] = 0.f;
#pragma unroll
    for (int k = 0; k < 12; ++k) sf2[k] = 0.f;
#pragma unroll
    for (int s = 0; s < NOFF; ++s) crS[s] = 0.f;

    // A prefetch registers: [round parity][channel-in-pair]; indices static
    // after full unroll (rule: no runtime-indexed reg arrays).
    float4 aP[2][2];
    aP[0][0] = *(const float4*)(AG + 0 * HW);
    aP[0][1] = *(const float4*)(AG + 1 * HW);

    // Prologue stage: channels 0,1 into buffer 0. Each wave stages 1KB/channel.
    stage16(FG + 0 * HW + wid * 256 + lane * 4, &fbuf[0][0][wid * 256]);
    stage16(FG + 1 * HW + wid * 256 + lane * 4, &fbuf[0][1][wid * 256]);

#pragma unroll
    for (int r = 0; r < 4; ++r) {
        __syncthreads();   // stage for round r complete (all waves); prev reads done

        if (r < 3) {
            // issue next round's stage + A prefetch early; they complete under
            // this round's compute (drained by next barrier)
            const int c0 = 2 * r + 2;
            stage16(FG + (c0    ) * HW + wid * 256 + lane * 4, &fbuf[(r + 1) & 1][0][wid * 256]);
            stage16(FG + (c0 + 1) * HW + wid * 256 + lane * 4, &fbuf[(r + 1) & 1][1][wid * 256]);
            aP[(r + 1) & 1][0] = *(const float4*)(AG + (c0    ) * HW);
            aP[(r + 1) & 1][1] = *(const float4*)(AG + (c0 + 1) * HW);
        }

#pragma unroll
        for (int q = 0; q < 2; ++q) {
            const float* fb = &fbuf[r & 1][q][lrow];
            float4 f0 = *(const float4*)&fb[(lw - 4) & (NW - 1)];
            float4 f1 = *(const float4*)&fb[lw];
            float4 f2 = *(const float4*)&fb[(lw + 4) & (NW - 1)];
            float fbv[12] = {f0.x, f0.y, f0.z, f0.w,
                             f1.x, f1.y, f1.z, f1.w,
                             f2.x, f2.y, f2.z, f2.w};
            float4 a4 = aP[r & 1][q];
            float avr[4] = {a4.x, a4.y, a4.z, a4.w};

            float am[4], fm[12];
#pragma unroll
            for (int j = 0; j < 4; ++j) am[j] = avr[j] * m1f[j];
#pragma unroll
            for (int k = 0; k < 12; ++k) fm[k] = fbv[k] * m2f[k];

#pragma unroll
            for (int j = 0; j < 4; ++j) sa2[j] = fmaf(am[j], am[j], sa2[j]);
#pragma unroll
            for (int k = 0; k < 12; ++k) sf2[k] = fmaf(fm[k], fm[k], sf2[k]);
#pragma unroll
            for (int s = 0; s < NOFF; ++s) {
#pragma unroll
                for (int j = 0; j < 4; ++j) {
                    crS[s] = fmaf(am[j], fm[j + 8 - s], crS[s]);
                }
            }
        }
    }

    // ---- per-thread epilogue: apply mask coefficients ----
    float sx[NOFF], cxf[NOFF];
#pragma unroll
    for (int s = 0; s < NOFF; ++s) {
        float t = 0.f, cc = 0.f;
#pragma unroll
        for (int j = 0; j < 4; ++j) {
            const int k = j + 8 - s;
            t  = fmaf(m2f[k], sa2[j], t);
            t  = fmaf(m1f[j], sf2[k], t);
            cc = fmaf(m1f[j], m2f[k], cc);
        }
        sx[s]  = fmaf(-2.f, crS[s], t);
        cxf[s] = cc;
    }

    // ---- wave reduce -> LDS -> block reduce -> few atomics per block ----
#pragma unroll
    for (int s = 0; s < NOFF; ++s) sx[s] = wave_sum_f(sx[s]);
    if (cg == 0) {
#pragma unroll
        for (int s = 0; s < NOFF; ++s) cxf[s] = wave_sum_f(cxf[s]);
    }
    if (lane == 0) {
#pragma unroll
        for (int s = 0; s < NOFF; ++s) {
            red[wid][s] = sx[s];
            red[wid][9 + s] = cxf[s];
        }
    }
    __syncthreads();

    float* numws = ws + (pair ? WS_NUM_AN : WS_NUM_AP) + b * NOFF;
    float* cntws = ws + (pair ? WS_CNT_AN : WS_CNT_AP) + b * NOFF;
    const int i = threadIdx.x;
    if (i < 9) {
        float v = red[0][i] + red[1][i] + red[2][i] + red[3][i];
        atomicAdd(numws + i, v);
    } else if (i < 18 && cg == 0) {
        float v = red[0][i] + red[1][i] + red[2][i] + red[3][i];
        atomicAdd(cntws + (i - 9), v);
    }
}

// 1 block, 64 threads: thread b handles batch b; wave-reduce the mean.
__global__ void finish_kernel(const float* __restrict__ ws, float* __restrict__ out)
{
    const int b = threadIdx.x;   // 0..63
    const float* num_ap = ws + WS_NUM_AP;
    const float* num_an = ws + WS_NUM_AN;
    const float* cnt_ap = ws + WS_CNT_AP;
    const float* cnt_an = ws + WS_CNT_AN;

    float ap = 3.4e38f, an = 3.4e38f;
#pragma unroll
    for (int s = 0; s < NOFF; ++s) {
        ap = fminf(ap, num_ap[b * NOFF + s] / (16.f * cnt_ap[b * NOFF + s] + 0.001f));
        an = fminf(an, num_an[b * NOFF + s] / (16.f * cnt_an[b * NOFF + s] + 0.001f));
    }
    float loss = fmaxf(ap - an + 0.15f, 0.f);
    loss = wave_sum_f(loss);
    if (b == 0) out[0] = loss * (1.0f / 64.f);
}

extern "C" void kernel_launch(void* const* d_in, const int* in_sizes, int n_in,
                              void* d_out, int out_size, void* d_ws, size_t ws_size,
                              hipStream_t stream) {
    const float* a = (const float*)d_in[0];
    const float* p = (const float*)d_in[1];
    const float* n = (const float*)d_in[2];
    const int* ma = (const int*)d_in[3];
    const int* mp = (const int*)d_in[4];
    const int* mn = (const int*)d_in[5];
    float* ws = (float*)d_ws;
    float* out = (float*)d_out;

    // ws is poisoned 0xAA before every timed launch — zero the accumulators.
    hipMemsetAsync(d_ws, 0, WS_FLOATS * sizeof(float), stream);

    num_kernel<<<dim3(16, 4, NB), 256, 0, stream>>>(a, p, n, ma, mp, mn, ws);
    finish_kernel<<<1, 64, 0, stream>>>(ws, out);
}

// Round 6
// 209.507 us; speedup vs baseline: 1.1734x; 1.1734x over previous
//
#include <hip/hip_runtime.h>

// Problem: B=64, C=16, H=32, W=512, SHIFT=4 (9 offsets), MARGIN=0.15
#define NB 64
#define NC 16
#define NH 32
#define NW 512
#define HW (NH * NW)      // 16384
#define CHW (NC * HW)     // 262144
#define NOFF 9
#define NCPB 4            // channels per block (channel-split x4)

// ws layout (floats): num_ap[64*9] | num_an[64*9] | cnt_ap[64*9] | cnt_an[64*9]
#define WS_NUM_AP 0
#define WS_NUM_AN 576
#define WS_CNT_AP 1152
#define WS_CNT_AN 1728
#define WS_FLOATS 2304

__device__ __forceinline__ float wave_sum_f(float v) {
#pragma unroll
    for (int o = 32; o > 0; o >>= 1) v += __shfl_down(v, o, 64);
    return v;
}

// grid: (16, 8, 64).
//   blockIdx.x: position tile (4096 threads x 4 positions = HW)
//   blockIdx.y: bit0 = pair (0: a-p, 1: a-n), bits1-2 = channel group (4 ch each)
//   blockIdx.z: batch
//
// Round-4 pre-masked factorization (verified 82.6us):
//   sum_c m1*m2*(a-f_s)^2 = m2[k]*sa2'[j] + m1[j]*sf2'[k] - 2*crS[s]
// with a'=m1*a, f'=m2*f; 25 accumulators, no spill (VGPR 52, WRITE 384KB).
// Round-6 change: channel-split x4 (was x2). Counters showed latency-bound
// (VALU 22%, HBM 16%, Occ 37%, waves >85% stalled): double the wave supply,
// halve each wave's serial load->wait->compute chain. A/mask re-reads are
// L3-resident. Blocks sharing A differ by 16 in linear id (=0 mod 8 -> same
// XCD under round-robin), so L2 sharing survives without a swizzle.
__global__ __launch_bounds__(256, 4) void num_kernel(
    const float* __restrict__ a, const float* __restrict__ p,
    const float* __restrict__ n, const int* __restrict__ ma,
    const int* __restrict__ mp, const int* __restrict__ mn,
    float* __restrict__ ws)
{
    const int b    = blockIdx.z;
    const int pair = blockIdx.y & 1;        // 0 -> p, 1 -> n
    const int cg   = blockIdx.y >> 1;       // channel group: 0..3
    const int tid  = blockIdx.x * 256 + threadIdx.x;  // 0..4095
    const int pos0 = tid * 4;                          // multiple of 4, in [0, HW)
    const int w0   = pos0 & (NW - 1);
    const int row  = pos0 - w0;
    const int idxm = row + ((w0 - 4) & (NW - 1));      // aligned float4, row-circular
    const int idxp = row + ((w0 + 4) & (NW - 1));

    // ---- masks -> float multipliers (drive pre-masking) ----
    const int* MA = ma + b * HW;
    const int* M2 = (pair ? mn : mp) + b * HW;
    int4 mav = *(const int4*)(MA + pos0);
    int4 mf0 = *(const int4*)(M2 + idxm);
    int4 mf1 = *(const int4*)(M2 + pos0);
    int4 mf2 = *(const int4*)(M2 + idxp);

    float m1f[4]  = {mav.x ? 1.f : 0.f, mav.y ? 1.f : 0.f,
                     mav.z ? 1.f : 0.f, mav.w ? 1.f : 0.f};
    float m2f[12] = {mf0.x ? 1.f : 0.f, mf0.y ? 1.f : 0.f, mf0.z ? 1.f : 0.f, mf0.w ? 1.f : 0.f,
                     mf1.x ? 1.f : 0.f, mf1.y ? 1.f : 0.f, mf1.z ? 1.f : 0.f, mf1.w ? 1.f : 0.f,
                     mf2.x ? 1.f : 0.f, mf2.y ? 1.f : 0.f, mf2.z ? 1.f : 0.f, mf2.w ? 1.f : 0.f};

    const float* A = a + (size_t)b * CHW + (size_t)cg * NCPB * HW;
    const float* F = (pair ? n : p) + (size_t)b * CHW + (size_t)cg * NCPB * HW;

    float sa2[4];
    float sf2[12];
    float crS[NOFF];
#pragma unroll
    for (int j = 0; j < 4; ++j) sa2[j] = 0.f;
#pragma unroll
    for (int k = 0; k < 12; ++k) sf2[k] = 0.f;
#pragma unroll
    for (int s = 0; s < NOFF; ++s) crS[s] = 0.f;

    // ---- channel loop: 4 float4 loads, 16 muls, 52 FMAs; 25 accumulators ----
#pragma unroll 2
    for (int c = 0; c < NCPB; ++c) {
        const float* Ac = A + c * HW;
        const float* Fc = F + c * HW;

        float4 av4 = *(const float4*)(Ac + pos0);
        float fb[12];
        *(float4*)&fb[0] = *(const float4*)(Fc + idxm);
        *(float4*)&fb[4] = *(const float4*)(Fc + pos0);
        *(float4*)&fb[8] = *(const float4*)(Fc + idxp);
        float avr[4] = {av4.x, av4.y, av4.z, av4.w};

        float am[4], fm[12];
#pragma unroll
        for (int j = 0; j < 4; ++j) am[j] = avr[j] * m1f[j];
#pragma unroll
        for (int k = 0; k < 12; ++k) fm[k] = fb[k] * m2f[k];

#pragma unroll
        for (int j = 0; j < 4; ++j) sa2[j] = fmaf(am[j], am[j], sa2[j]);
#pragma unroll
        for (int k = 0; k < 12; ++k) sf2[k] = fmaf(fm[k], fm[k], sf2[k]);
#pragma unroll
        for (int s = 0; s < NOFF; ++s) {
#pragma unroll
            for (int j = 0; j < 4; ++j) {
                crS[s] = fmaf(am[j], fm[j + 8 - s], crS[s]);
            }
        }
    }

    // ---- per-thread epilogue: apply mask coefficients ----
    float sx[NOFF], cxf[NOFF];
#pragma unroll
    for (int s = 0; s < NOFF; ++s) {
        float t = 0.f, cc = 0.f;
#pragma unroll
        for (int j = 0; j < 4; ++j) {
            const int k = j + 8 - s;
            t  = fmaf(m2f[k], sa2[j], t);
            t  = fmaf(m1f[j], sf2[k], t);
            cc = fmaf(m1f[j], m2f[k], cc);
        }
        sx[s]  = fmaf(-2.f, crS[s], t);
        cxf[s] = cc;
    }

    // ---- wave reduce -> LDS -> block reduce -> few atomics per block ----
    __shared__ float red[4][20];           // [wave][9 num + 9 cnt], padded
    const int lane = threadIdx.x & 63;
    const int wid  = threadIdx.x >> 6;

#pragma unroll
    for (int s = 0; s < NOFF; ++s) sx[s] = wave_sum_f(sx[s]);
    if (cg == 0) {
#pragma unroll
        for (int s = 0; s < NOFF; ++s) cxf[s] = wave_sum_f(cxf[s]);
    }
    if (lane == 0) {
#pragma unroll
        for (int s = 0; s < NOFF; ++s) {
            red[wid][s] = sx[s];
            red[wid][9 + s] = cxf[s];
        }
    }
    __syncthreads();

    float* numws = ws + (pair ? WS_NUM_AN : WS_NUM_AP) + b * NOFF;
    float* cntws = ws + (pair ? WS_CNT_AN : WS_CNT_AP) + b * NOFF;
    const int i = threadIdx.x;
    if (i < 9) {
        float v = red[0][i] + red[1][i] + red[2][i] + red[3][i];
        atomicAdd(numws + i, v);
    } else if (i < 18 && cg == 0) {
        float v = red[0][i] + red[1][i] + red[2][i] + red[3][i];
        atomicAdd(cntws + (i - 9), v);
    }
}

// 1 block, 64 threads: thread b handles batch b; wave-reduce the mean.
__global__ void finish_kernel(const float* __restrict__ ws, float* __restrict__ out)
{
    const int b = threadIdx.x;   // 0..63
    const float* num_ap = ws + WS_NUM_AP;
    const float* num_an = ws + WS_NUM_AN;
    const float* cnt_ap = ws + WS_CNT_AP;
    const float* cnt_an = ws + WS_CNT_AN;

    float ap = 3.4e38f, an = 3.4e38f;
#pragma unroll
    for (int s = 0; s < NOFF; ++s) {
        ap = fminf(ap, num_ap[b * NOFF + s] / (16.f * cnt_ap[b * NOFF + s] + 0.001f));
        an = fminf(an, num_an[b * NOFF + s] / (16.f * cnt_an[b * NOFF + s] + 0.001f));
    }
    float loss = fmaxf(ap - an + 0.15f, 0.f);
    loss = wave_sum_f(loss);
    if (b == 0) out[0] = loss * (1.0f / 64.f);
}

extern "C" void kernel_launch(void* const* d_in, const int* in_sizes, int n_in,
                              void* d_out, int out_size, void* d_ws, size_t ws_size,
                              hipStream_t stream) {
    const float* a = (const float*)d_in[0];
    const float* p = (const float*)d_in[1];
    const float* n = (const float*)d_in[2];
    const int* ma = (const int*)d_in[3];
    const int* mp = (const int*)d_in[4];
    const int* mn = (const int*)d_in[5];
    float* ws = (float*)d_ws;
    float* out = (float*)d_out;

    // ws is poisoned 0xAA before every timed launch — zero the accumulators.
    hipMemsetAsync(d_ws, 0, WS_FLOATS * sizeof(float), stream);

    num_kernel<<<dim3(16, 8, NB), 256, 0, stream>>>(a, p, n, ma, mp, mn, ws);
    finish_kernel<<<1, 64, 0, stream>>>(ws, out);
}